// Round 5
// baseline (3309.645 us; speedup 1.0000x reference)
//
#include <hip/hip_runtime.h>

// ---------------------------------------------------------------------------
// Part_Graph: deformable-conv message passing over a 6-node part graph.
// B=2, H=W=96, IN=256, HID=10, P=6, E=12, K=9 taps.  ALL I/O is float32.
// ---------------------------------------------------------------------------

#define NE 12
#define NPART 6
#define BB 2
#define HH 96
#define WW 96
#define HWD (HH*WW)          // 9216
#define CIN2 20              // 2*HID concat channels
#define NHID 10
#define NIN 256

// LDS tile geometry: 16x16 output tile, +-2 halo -> 20x20 box.
#define BOX 20
#define BCOL 21              // padded col stride (bank stagger)
#define PLANE (BOX*BCOL*4)   // floats per 4-channel plane = 1680

__device__ __forceinline__ float sigf(float x) { return 1.f / (1.f + __expf(-x)); }

// ---------------------------------------------------------------------------
// Weight transposition to hot-loop friendly layouts (fp32 -> fp32):
//   off*_wt : [e][t=9][c=20][o=27]   (conv: per tap, n[c] dot into om[o])
//   dcn*_wt : [e][k=9][c=20][o]      (sampling: per (k,c) matvec over o)
//   upd_wt  : [p][c=256][o=10]
// ---------------------------------------------------------------------------
__global__ __launch_bounds__(256)
void xpose_weights(const float* __restrict__ off1_w, const float* __restrict__ off1_b,
                   const float* __restrict__ dcn1_w,
                   const float* __restrict__ off2_w, const float* __restrict__ off2_b,
                   const float* __restrict__ dcn2_w,
                   const float* __restrict__ upd_w,
                   float* __restrict__ o1wt, float* __restrict__ o1b, float* __restrict__ d1wt,
                   float* __restrict__ o2wt, float* __restrict__ o2b, float* __restrict__ d2wt,
                   float* __restrict__ uwt)
{
    int idx = blockIdx.x * 256 + threadIdx.x;
    if (idx < 58320) {                       // off1_wt [e][t][c][o]
        int e = idx / 4860, r = idx % 4860;
        int t = r / 540, r2 = r % 540, c = r2 / 27, o = r2 % 27;
        o1wt[idx] = off1_w[((e*27 + o)*CIN2 + c)*9 + t];
        return;
    }
    idx -= 58320;
    if (idx < 324) { o1b[idx] = off1_b[idx]; return; }
    idx -= 324;
    if (idx < 43200) {                       // dcn1_wt [e][k][c][o]
        int e = idx / 3600, r = idx % 3600;
        int k = r / 400, r2 = r % 400, c = r2 / 20, o = r2 % 20;
        d1wt[idx] = dcn1_w[((e*20 + o)*20 + c)*9 + k];
        return;
    }
    idx -= 43200;
    if (idx < 58320) {                       // off2_wt [e][t][c][o]
        int e = idx / 4860, r = idx % 4860;
        int t = r / 540, r2 = r % 540, c = r2 / 27, o = r2 % 27;
        o2wt[idx] = off2_w[((e*27 + o)*CIN2 + c)*9 + t];
        return;
    }
    idx -= 58320;
    if (idx < 324) { o2b[idx] = off2_b[idx]; return; }
    idx -= 324;
    if (idx < 21600) {                       // dcn2_wt [e][k][c][o=10]
        int e = idx / 1800, r = idx % 1800;
        int k = r / 200, r2 = r % 200, c = r2 / 10, o = r2 % 10;
        d2wt[idx] = dcn2_w[((e*10 + o)*20 + c)*9 + k];
        return;
    }
    idx -= 21600;
    if (idx < 15360) {                       // upd_wt [p][c][o]
        int p = idx / 2560, r = idx % 2560, c = r / 10, o = r % 10;
        uwt[idx] = upd_w[(p*10 + o)*256 + c];
        return;
    }
}

// ---------------------------------------------------------------------------
// Fused, LDS-tiled DCNv2 layer (ILP-pipelined).
// 16x16 px tile/block; 20x20 halo box, 20 ch as 5 float4-planes in LDS.
// grid: (36, B, E); 4 blocks/CU (33.6 KB LDS), VGPR cap 128.
// ---------------------------------------------------------------------------
template<int COUT, bool L1>
__global__ __launch_bounds__(256, 4)
void dcn_tiled(const float* __restrict__ xin_all,
               const float* __restrict__ xp,      // only for L1 gather
               const int* __restrict__ esrc, const int* __restrict__ edst,
               const float* __restrict__ wo_all,  // [E][9][20][27]
               const float* __restrict__ bo_all,  // [E][27]
               const float* __restrict__ wd_all,  // [E][9][20][COUT]
               const float* __restrict__ bnS, const float* __restrict__ bnT,
               float* __restrict__ out)
{
    const int b = blockIdx.y, e = blockIdx.z;
    const int ty0 = (blockIdx.x / 6) * 16, tx0 = (blockIdx.x % 6) * 16;
    const int tid = threadIdx.x;
    const int ly = tid >> 4, lx = tid & 15;
    const int h = ty0 + ly, w = tx0 + lx;
    const int r0 = ty0 - 2, c0 = tx0 - 2;          // staged box origin

    const float* __restrict__ xin = xin_all + (size_t)(e*BB + b)*CIN2*HWD;
    const float* __restrict__ wo  = wo_all + (size_t)e*9*CIN2*27;
    const float* __restrict__ bo  = bo_all + e*27;
    const float* __restrict__ wd  = wd_all + (size_t)e*9*CIN2*COUT;

    __shared__ float lds[5*PLANE];                 // 33.6 KB

    // ---- stage ----
    #pragma unroll 1
    for (int c = 0; c < CIN2; c++) {
        const float* src;
        float sc = 1.f, sh = 0.f;
        if (L1) {
            int part = (c < NHID) ? esrc[e] : edst[e];
            int ch   = (c < NHID) ? c : c - NHID;
            src = xp + ((size_t)(part*BB + b)*NHID + ch)*HWD;
        } else {
            src = xin + (size_t)c*HWD;
            sc = bnS[e*CIN2 + c]; sh = bnT[e*CIN2 + c];
        }
        float* plane = lds + (c >> 2)*PLANE;
        int cl = (c & 3);
        for (int i = tid; i < BOX*BOX; i += 256) {
            int rr = i / BOX, cc = i % BOX;
            int y = r0 + rr, x = c0 + cc;
            float v = 0.f;
            if (y >= 0 && y < HH && x >= 0 && x < WW) {
                v = src[y*WW + x];
                if (!L1) v = fmaxf(fmaf(v, sc, sh), 0.f);
            }
            plane[(rr*BCOL + cc)*4 + cl] = v;
        }
    }
    __syncthreads();

    // ---- offset conv: om[27] ----
    float om[27];
    #pragma unroll
    for (int o = 0; o < 27; o++) om[o] = bo[o];

    #pragma unroll
    for (int t = 0; t < 9; t++) {
        const int rr = ly + 2 + (t/3) - 1, cc = lx + 2 + (t%3) - 1;
        const int pix = (rr*BCOL + cc)*4;
        const float* wt = wo + t*CIN2*27;
        // load all 20 channels for this tap up front, then one long FMA run
        float4 n0 = *reinterpret_cast<const float4*>(&lds[0*PLANE + pix]);
        float4 n1 = *reinterpret_cast<const float4*>(&lds[1*PLANE + pix]);
        float4 n2 = *reinterpret_cast<const float4*>(&lds[2*PLANE + pix]);
        float4 n3 = *reinterpret_cast<const float4*>(&lds[3*PLANE + pix]);
        float4 n4 = *reinterpret_cast<const float4*>(&lds[4*PLANE + pix]);
        #pragma unroll
        for (int c4 = 0; c4 < 5; c4++) {
            float4 nv4 = (c4 == 0) ? n0 : (c4 == 1) ? n1 : (c4 == 2) ? n2
                        : (c4 == 3) ? n3 : n4;
            #pragma unroll
            for (int j = 0; j < 4; j++) {
                float nv = (&nv4.x)[j];
                const float* wc = wt + (c4*4 + j)*27;
                #pragma unroll
                for (int o = 0; o < 27; o++) om[o] = fmaf(nv, wc[o], om[o]);
            }
        }
    }

    // ---- deformable sampling + tap matvec ----
    float acc[COUT];
    #pragma unroll
    for (int o = 0; o < COUT; o++) acc[o] = 0.f;

    #pragma unroll
    for (int k = 0; k < 9; k++) {
        float m  = sigf(om[18 + k]);
        float ys = (float)(h + k/3 - 1) + om[2*k];
        float xs = (float)(w + k%3 - 1) + om[2*k + 1];
        float y0f = floorf(ys), x0f = floorf(xs);
        int iy = (int)y0f, ix = (int)x0f;
        float fy = ys - y0f, fx = xs - x0f;
        bool vy0 = (iy >= 0) && (iy < HH);
        bool vy1 = (iy >= -1) && (iy < HH-1);
        bool vx0 = (ix >= 0) && (ix < WW);
        bool vx1 = (ix >= -1) && (ix < WW-1);
        float w00 = (vy0 && vx0) ? (1.f-fy)*(1.f-fx)*m : 0.f;
        float w01 = (vy0 && vx1) ? (1.f-fy)*fx*m       : 0.f;
        float w10 = (vy1 && vx0) ? fy*(1.f-fx)*m       : 0.f;
        float w11 = (vy1 && vx1) ? fy*fx*m             : 0.f;
        int cy0 = min(max(iy,   0), HH-1), cy1 = min(max(iy+1, 0), HH-1);
        int cx0 = min(max(ix,   0), WW-1), cx1 = min(max(ix+1, 0), WW-1);
        const float* wk = wd + k*CIN2*COUT;

        bool staged = (cy0 >= r0) && (cy1 <= r0 + BOX-1) &&
                      (cx0 >= c0) && (cx1 <= c0 + BOX-1);
        if (staged) {
            const int p00 = ((cy0-r0)*BCOL + (cx0-c0))*4;
            const int p01 = ((cy0-r0)*BCOL + (cx1-c0))*4;
            const int p10 = ((cy1-r0)*BCOL + (cx0-c0))*4;
            const int p11 = ((cy1-r0)*BCOL + (cx1-c0))*4;
            // 2-stage software pipeline over the 5 channel chunks
            float4 a  = *reinterpret_cast<const float4*>(lds + p00);
            float4 bq = *reinterpret_cast<const float4*>(lds + p01);
            float4 cq = *reinterpret_cast<const float4*>(lds + p10);
            float4 dq = *reinterpret_cast<const float4*>(lds + p11);
            #pragma unroll
            for (int c4 = 0; c4 < 5; c4++) {
                float4 a2, b2, c2, d2;
                if (c4 < 4) {
                    const float* pl = lds + (c4+1)*PLANE;
                    a2 = *reinterpret_cast<const float4*>(pl + p00);
                    b2 = *reinterpret_cast<const float4*>(pl + p01);
                    c2 = *reinterpret_cast<const float4*>(pl + p10);
                    d2 = *reinterpret_cast<const float4*>(pl + p11);
                }
                #pragma unroll
                for (int j = 0; j < 4; j++) {
                    float s = w00*(&a.x)[j] + w01*(&bq.x)[j]
                            + w10*(&cq.x)[j] + w11*(&dq.x)[j];
                    const float* wc = wk + (c4*4 + j)*COUT;
                    #pragma unroll
                    for (int o = 0; o < COUT; o++) acc[o] = fmaf(s, wc[o], acc[o]);
                }
                if (c4 < 4) { a = a2; bq = b2; cq = c2; dq = d2; }
            }
        } else {
            int o00 = cy0*WW + cx0, o01 = cy0*WW + cx1;
            int o10 = cy1*WW + cx0, o11 = cy1*WW + cx1;
            #pragma unroll 1
            for (int c = 0; c < CIN2; c++) {
                const float* src;
                float sc = 1.f, sh = 0.f;
                if (L1) {
                    int part = (c < NHID) ? esrc[e] : edst[e];
                    int ch   = (c < NHID) ? c : c - NHID;
                    src = xp + ((size_t)(part*BB + b)*NHID + ch)*HWD;
                } else {
                    src = xin + (size_t)c*HWD;
                    sc = bnS[e*CIN2 + c]; sh = bnT[e*CIN2 + c];
                }
                float av = src[o00], bv = src[o01], cv = src[o10], dv = src[o11];
                if (!L1) {
                    av = fmaxf(fmaf(av, sc, sh), 0.f); bv = fmaxf(fmaf(bv, sc, sh), 0.f);
                    cv = fmaxf(fmaf(cv, sc, sh), 0.f); dv = fmaxf(fmaf(dv, sc, sh), 0.f);
                }
                float s = w00*av + w01*bv + w10*cv + w11*dv;
                const float* wc = wk + c*COUT;
                #pragma unroll
                for (int o = 0; o < COUT; o++) acc[o] = fmaf(s, wc[o], acc[o]);
            }
        }
    }

    float* op = out + ((size_t)(e*BB + b)*COUT)*HWD + h*WW + w;
    #pragma unroll
    for (int o = 0; o < COUT; o++) op[(size_t)o*HWD] = acc[o];
}

// ---------------------------------------------------------------------------
// BN statistics (training mode, biased var, eps=1e-5), folding gamma/beta:
//   scale = g*rstd, shift = beta - mean*scale
// ---------------------------------------------------------------------------
__device__ __forceinline__ void bn_finish(float s1, float s2, int n, float g, float bt,
                                          float* scale, float* shift, int idx)
{
    float mean = s1 / (float)n;
    float var  = fmaxf(s2 / (float)n - mean*mean, 0.f);
    float rs   = rsqrtf(var + 1e-5f);
    scale[idx] = g * rs;
    shift[idx] = bt - mean * g * rs;
}

// stats over flat layout [G][B][C][HWD]; one block per (g,c); grid = G*C
template<int C>
__global__ __launch_bounds__(256)
void bn_stats_flat(const float* __restrict__ x, const float* __restrict__ gamma,
                   const float* __restrict__ beta, float* __restrict__ scale,
                   float* __restrict__ shift)
{
    const int gc = blockIdx.x;
    const int g = gc / C, c = gc % C;
    const int N = BB * HWD;
    float s1 = 0.f, s2 = 0.f;
    for (int idx = threadIdx.x; idx < N; idx += 256) {
        int b = idx / HWD, p = idx % HWD;
        float v = x[((size_t)(g*BB + b)*C + c)*HWD + p];
        s1 += v; s2 += v*v;
    }
    __shared__ float r1[256], r2[256];
    r1[threadIdx.x] = s1; r2[threadIdx.x] = s2;
    __syncthreads();
    for (int s = 128; s > 0; s >>= 1) {
        if (threadIdx.x < s) { r1[threadIdx.x] += r1[threadIdx.x+s]; r2[threadIdx.x] += r2[threadIdx.x+s]; }
        __syncthreads();
    }
    if (threadIdx.x == 0)
        bn_finish(r1[0], r2[0], N, gamma[gc], beta[gc], scale, shift, gc);
}

// ---------------------------------------------------------------------------
// Edge message: msg = sigmoid(out_w . relu(bn2(t2)) + out_b) *
//                     (1 - sigmoid(a_w . xp[src] + a_b))
// grid: (36, B, E)
// ---------------------------------------------------------------------------
__global__ __launch_bounds__(256)
void msg_kernel(const float* __restrict__ t2, const float* __restrict__ s2,
                const float* __restrict__ sh2, const float* __restrict__ o_w,
                const float* __restrict__ o_b, const float* __restrict__ a_w,
                const float* __restrict__ a_b, const float* __restrict__ xp,
                const int* __restrict__ esrc, float* __restrict__ msg)
{
    int px = blockIdx.x * 256 + threadIdx.x;
    int b = blockIdx.y, e = blockIdx.z;
    float sab = o_b[e];
    #pragma unroll
    for (int c = 0; c < NHID; c++) {
        float v = t2[((size_t)(e*BB + b)*NHID + c)*HWD + px];
        v = fmaxf(fmaf(v, s2[e*NHID+c], sh2[e*NHID+c]), 0.f);
        sab += v * o_w[e*NHID + c];
    }
    int sp = esrc[e];
    float sa = a_b[e];
    #pragma unroll
    for (int c = 0; c < NHID; c++)
        sa += xp[((size_t)(sp*BB + b)*NHID + c)*HWD + px] * a_w[e*NHID + c];
    msg[((size_t)e*BB + b)*HWD + px] = sigf(sab) * (1.f - sigf(sa));
}

// ---------------------------------------------------------------------------
// gate[p,b,hw] = 1 + decomp + self_att + sum_{e: dst==p} msg[e]
// grid: (36, B, P)
// ---------------------------------------------------------------------------
__global__ __launch_bounds__(256)
void gate_kernel(const float* __restrict__ xp, const float* __restrict__ xh,
                 const float* __restrict__ att_w, const float* __restrict__ att_b,
                 const float* __restrict__ du_w, const float* __restrict__ du_b,
                 const float* __restrict__ dl_w, const float* __restrict__ dl_b,
                 const int* __restrict__ edst, const float* __restrict__ msg,
                 float* __restrict__ gate)
{
    int px = blockIdx.x * 256 + threadIdx.x;
    int b = blockIdx.y, p = blockIdx.z;
    float s = att_b[p];
    #pragma unroll
    for (int c = 0; c < NHID; c++)
        s += xp[((size_t)(p*BB + b)*NHID + c)*HWD + px] * att_w[p*NHID + c];
    float satt = sigf(s);
    int hs = (p < 4) ? 0 : 1;
    const float* dw = (p < 4) ? du_w : dl_w;
    float d = (p < 4) ? du_b[0] : dl_b[0];
    #pragma unroll
    for (int c = 0; c < NHID; c++)
        d += xh[((size_t)(hs*BB + b)*NHID + c)*HWD + px] * dw[c];
    float dec = sigf(d);
    float xpp = 0.f;
    for (int e = 0; e < NE; e++)
        if (edst[e] == p) xpp += msg[((size_t)e*BB + b)*HWD + px];
    gate[((size_t)p*BB + b)*HWD + px] = 1.f + dec + satt + xpp;
}

// ---------------------------------------------------------------------------
// y[p,b,o,hw] = gate[p,b,hw] * sum_c p_fea[b,c,hw] * upd_w[p,o,c]
// grid: (36, B, P)
// ---------------------------------------------------------------------------
__global__ __launch_bounds__(256)
void q_kernel(const float* __restrict__ p_fea, const float* __restrict__ wq_all,
              const float* __restrict__ gate, float* __restrict__ y)
{
    int px = blockIdx.x * 256 + threadIdx.x;
    int b = blockIdx.y, p = blockIdx.z;
    const float* wq = wq_all + (size_t)p*NIN*NHID;     // [c][o]
    const float* pf = p_fea + (size_t)b*NIN*HWD + px;
    float acc[NHID];
    #pragma unroll
    for (int o = 0; o < NHID; o++) acc[o] = 0.f;
    for (int c = 0; c < NIN; c++) {
        float v = pf[(size_t)c*HWD];
        const float* wc = wq + c*NHID;
        #pragma unroll
        for (int o = 0; o < NHID; o++) acc[o] = fmaf(v, wc[o], acc[o]);
    }
    float g = gate[((size_t)p*BB + b)*HWD + px];
    float* yp = y + ((size_t)(p*BB + b)*NHID)*HWD + px;
    #pragma unroll
    for (int o = 0; o < NHID; o++) yp[(size_t)o*HWD] = acc[o] * g;
}

// ---------------------------------------------------------------------------
// out = relu(bn5(y));   grid: (36, B*HID, P)
// ---------------------------------------------------------------------------
__global__ __launch_bounds__(256)
void out_kernel(const float* __restrict__ y, const float* __restrict__ s5,
                const float* __restrict__ t5, float* __restrict__ out)
{
    int px = blockIdx.x * 256 + threadIdx.x;
    int bo = blockIdx.y, p = blockIdx.z;
    int b = bo / NHID, o = bo % NHID;
    size_t idx = ((size_t)(p*BB + b)*NHID + o)*HWD + px;
    out[idx] = fmaxf(fmaf(y[idx], s5[p*NHID+o], t5[p*NHID+o]), 0.f);
}

// ---------------------------------------------------------------------------
// launcher
// ---------------------------------------------------------------------------
extern "C" void kernel_launch(void* const* d_in, const int* in_sizes, int n_in,
                              void* d_out, int out_size, void* d_ws, size_t ws_size,
                              hipStream_t stream)
{
    (void)in_sizes; (void)n_in; (void)out_size; (void)ws_size;

    const float* p_fea  = (const float*)d_in[0];
    const float* xp     = (const float*)d_in[1];
    const float* xh     = (const float*)d_in[2];
    const float* att_w  = (const float*)d_in[3];
    const float* att_b  = (const float*)d_in[4];
    const float* du_w   = (const float*)d_in[5];
    const float* du_b   = (const float*)d_in[6];
    const float* dl_w   = (const float*)d_in[7];
    const float* dl_b   = (const float*)d_in[8];
    const float* upd_w  = (const float*)d_in[9];
    const float* upd_g  = (const float*)d_in[10];
    const float* upd_b  = (const float*)d_in[11];
    const float* off1_w = (const float*)d_in[12];
    const float* off1_b = (const float*)d_in[13];
    const float* dcn1_w = (const float*)d_in[14];
    const float* bn1_g  = (const float*)d_in[15];
    const float* bn1_b  = (const float*)d_in[16];
    const float* off2_w = (const float*)d_in[17];
    const float* off2_b = (const float*)d_in[18];
    const float* dcn2_w = (const float*)d_in[19];
    const float* bn2_g  = (const float*)d_in[20];
    const float* bn2_b  = (const float*)d_in[21];
    const float* out_w  = (const float*)d_in[22];
    const float* out_b  = (const float*)d_in[23];
    const float* aatt_w = (const float*)d_in[24];
    const float* aatt_b = (const float*)d_in[25];
    const int* esrc     = (const int*)d_in[26];
    const int* edst     = (const int*)d_in[27];
    float* outp = (float*)d_out;
    float* ws = (float*)d_ws;

    // workspace layout (float offsets)
    constexpr size_t o_x1   = 0;                                    // [E][B][20][HWD]
    constexpr size_t o_t2   = o_x1  + (size_t)NE*BB*CIN2*HWD;       // [E][B][10][HWD]
    constexpr size_t o_msg  = o_t2  + (size_t)NE*BB*NHID*HWD;
    constexpr size_t o_gate = o_msg  + (size_t)NE*BB*HWD;
    constexpr size_t o_w1   = o_gate + (size_t)NPART*BB*HWD;
    constexpr size_t o_b1   = o_w1   + 58320;
    constexpr size_t o_d1   = o_b1   + 324;
    constexpr size_t o_w2   = o_d1   + 43200;
    constexpr size_t o_b2   = o_w2   + 58320;
    constexpr size_t o_d2   = o_b2   + 324;
    constexpr size_t o_uw   = o_d2   + 21600;
    constexpr size_t o_bn1s = o_uw   + 15360;
    constexpr size_t o_bn1t = o_bn1s + NE*CIN2;
    constexpr size_t o_bn2s = o_bn1t + NE*CIN2;
    constexpr size_t o_bn2t = o_bn2s + NE*NHID;
    constexpr size_t o_bn5s = o_bn2t + NE*NHID;
    constexpr size_t o_bn5t = o_bn5s + NPART*NHID;
    constexpr size_t o_y    = o_bn5t + NPART*NHID;                  // [P][B][10][HWD]
    float* x1 = ws + o_x1;
    float* t2 = ws + o_t2;
    float* y  = ws + o_y;

    xpose_weights<<<dim3(772), 256, 0, stream>>>(
        off1_w, off1_b, dcn1_w, off2_w, off2_b, dcn2_w, upd_w,
        ws+o_w1, ws+o_b1, ws+o_d1, ws+o_w2, ws+o_b2, ws+o_d2, ws+o_uw);

    dcn_tiled<CIN2, true><<<dim3(36, BB, NE), 256, 0, stream>>>(
        nullptr, xp, esrc, edst, ws+o_w1, ws+o_b1, ws+o_d1,
        nullptr, nullptr, x1);

    bn_stats_flat<CIN2><<<dim3(NE*CIN2), 256, 0, stream>>>(
        x1, bn1_g, bn1_b, ws+o_bn1s, ws+o_bn1t);

    dcn_tiled<NHID, false><<<dim3(36, BB, NE), 256, 0, stream>>>(
        x1, nullptr, esrc, edst, ws+o_w2, ws+o_b2, ws+o_d2,
        ws+o_bn1s, ws+o_bn1t, t2);

    bn_stats_flat<NHID><<<dim3(NE*NHID), 256, 0, stream>>>(
        t2, bn2_g, bn2_b, ws+o_bn2s, ws+o_bn2t);

    msg_kernel<<<dim3(36, BB, NE), 256, 0, stream>>>(
        t2, ws+o_bn2s, ws+o_bn2t, out_w, out_b, aatt_w, aatt_b, xp, esrc, ws+o_msg);

    gate_kernel<<<dim3(36, BB, NPART), 256, 0, stream>>>(
        xp, xh, att_w, att_b, du_w, du_b, dl_w, dl_b, edst, ws+o_msg, ws+o_gate);

    q_kernel<<<dim3(36, BB, NPART), 256, 0, stream>>>(
        p_fea, ws+o_uw, ws+o_gate, y);

    bn_stats_flat<NHID><<<dim3(NPART*NHID), 256, 0, stream>>>(
        y, upd_g, upd_b, ws+o_bn5s, ws+o_bn5t);

    out_kernel<<<dim3(36, BB*NHID, NPART), 256, 0, stream>>>(
        y, ws+o_bn5s, ws+o_bn5t, outp);
}

// Round 6
// 298.123 us; speedup vs baseline: 11.1016x; 11.1016x over previous
//
#include <hip/hip_runtime.h>

// ---------------------------------------------------------------------------
// Part_Graph: deformable-conv message passing over a 6-node part graph.
// B=2, H=W=96, IN=256, HID=10, P=6, E=12, K=9 taps.  ALL I/O is float32.
// ---------------------------------------------------------------------------

#define NE 12
#define NPART 6
#define BB 2
#define HH 96
#define WW 96
#define HWD (HH*WW)          // 9216
#define CIN2 20              // 2*HID concat channels
#define NHID 10
#define NIN 256

// LDS tile geometry: 16x16 output tile, +-2 halo -> 20x20 box.
#define BOX 20
#define BCOL 21              // padded col stride (bank stagger)
#define PLANE (BOX*BCOL*4)   // floats per 4-channel plane = 1680

__device__ __forceinline__ float sigf(float x) { return 1.f / (1.f + __expf(-x)); }

// ---------------------------------------------------------------------------
// Weight transposition to hot-loop friendly layouts (fp32 -> fp32):
//   off*_wt : [e][t=9][c=20][o=27]   (conv: per tap, n[c] dot into om[o])
//   dcn*_wt : [e][k=9][c=20][o]      (sampling: per (k,c) matvec over o)
//   upd_wt  : [p][c=256][o=10]
// ---------------------------------------------------------------------------
__global__ __launch_bounds__(256)
void xpose_weights(const float* __restrict__ off1_w, const float* __restrict__ off1_b,
                   const float* __restrict__ dcn1_w,
                   const float* __restrict__ off2_w, const float* __restrict__ off2_b,
                   const float* __restrict__ dcn2_w,
                   const float* __restrict__ upd_w,
                   float* __restrict__ o1wt, float* __restrict__ o1b, float* __restrict__ d1wt,
                   float* __restrict__ o2wt, float* __restrict__ o2b, float* __restrict__ d2wt,
                   float* __restrict__ uwt)
{
    int idx = blockIdx.x * 256 + threadIdx.x;
    if (idx < 58320) {                       // off1_wt [e][t][c][o]
        int e = idx / 4860, r = idx % 4860;
        int t = r / 540, r2 = r % 540, c = r2 / 27, o = r2 % 27;
        o1wt[idx] = off1_w[((e*27 + o)*CIN2 + c)*9 + t];
        return;
    }
    idx -= 58320;
    if (idx < 324) { o1b[idx] = off1_b[idx]; return; }
    idx -= 324;
    if (idx < 43200) {                       // dcn1_wt [e][k][c][o]
        int e = idx / 3600, r = idx % 3600;
        int k = r / 400, r2 = r % 400, c = r2 / 20, o = r2 % 20;
        d1wt[idx] = dcn1_w[((e*20 + o)*20 + c)*9 + k];
        return;
    }
    idx -= 43200;
    if (idx < 58320) {                       // off2_wt [e][t][c][o]
        int e = idx / 4860, r = idx % 4860;
        int t = r / 540, r2 = r % 540, c = r2 / 27, o = r2 % 27;
        o2wt[idx] = off2_w[((e*27 + o)*CIN2 + c)*9 + t];
        return;
    }
    idx -= 58320;
    if (idx < 324) { o2b[idx] = off2_b[idx]; return; }
    idx -= 324;
    if (idx < 21600) {                       // dcn2_wt [e][k][c][o=10]
        int e = idx / 1800, r = idx % 1800;
        int k = r / 200, r2 = r % 200, c = r2 / 10, o = r2 % 10;
        d2wt[idx] = dcn2_w[((e*10 + o)*20 + c)*9 + k];
        return;
    }
    idx -= 21600;
    if (idx < 15360) {                       // upd_wt [p][c][o]
        int p = idx / 2560, r = idx % 2560, c = r / 10, o = r % 10;
        uwt[idx] = upd_w[(p*10 + o)*256 + c];
        return;
    }
}

// ---------------------------------------------------------------------------
// Fused, LDS-tiled DCNv2 layer.
// 16x16 px tile/block; 20x20 halo box, 20 ch as 5 float4-planes in LDS.
// ILP: rotation-prefetch with unroll(1) loops (bounded live set, no spill).
// grid: (36, B, E); 4 blocks/CU (33.6 KB LDS), VGPR cap 128.
// ---------------------------------------------------------------------------
template<int COUT, bool L1>
__global__ __launch_bounds__(256, 4)
void dcn_tiled(const float* __restrict__ xin_all,
               const float* __restrict__ xp,      // only for L1 gather
               const int* __restrict__ esrc, const int* __restrict__ edst,
               const float* __restrict__ wo_all,  // [E][9][20][27]
               const float* __restrict__ bo_all,  // [E][27]
               const float* __restrict__ wd_all,  // [E][9][20][COUT]
               const float* __restrict__ bnS, const float* __restrict__ bnT,
               float* __restrict__ out)
{
    const int b = blockIdx.y, e = blockIdx.z;
    const int ty0 = (blockIdx.x / 6) * 16, tx0 = (blockIdx.x % 6) * 16;
    const int tid = threadIdx.x;
    const int ly = tid >> 4, lx = tid & 15;
    const int h = ty0 + ly, w = tx0 + lx;
    const int r0 = ty0 - 2, c0 = tx0 - 2;          // staged box origin

    const float* __restrict__ xin = xin_all + (size_t)(e*BB + b)*CIN2*HWD;
    const float* __restrict__ wo  = wo_all + (size_t)e*9*CIN2*27;
    const float* __restrict__ bo  = bo_all + e*27;
    const float* __restrict__ wd  = wd_all + (size_t)e*9*CIN2*COUT;

    __shared__ float lds[5*PLANE];                 // 33.6 KB

    // ---- stage: 2000 float4 quads = 20ch x 20rows x 5 ----
    #pragma unroll 1
    for (int i = tid; i < 2000; i += 256) {
        int c   = i / 100;
        int rem = i - c*100;
        int rr  = rem / 5;
        int q   = rem - rr*5;
        const float* src;
        float sc = 1.f, sh = 0.f;
        if (L1) {
            int part = (c < NHID) ? esrc[e] : edst[e];
            int ch   = (c < NHID) ? c : c - NHID;
            src = xp + ((size_t)(part*BB + b)*NHID + ch)*HWD;
        } else {
            src = xin + (size_t)c*HWD;
            sc = bnS[e*CIN2 + c]; sh = bnT[e*CIN2 + c];
        }
        int y = r0 + rr, xb = c0 + 4*q;
        float4 v = make_float4(0.f, 0.f, 0.f, 0.f);
        if (y >= 0 && y < HH) {
            const float* row = src + y*WW;
            if (xb >= 0 && xb + 3 < WW) {
                v = *reinterpret_cast<const float4*>(row + xb);
            } else {
                if (xb+0 >= 0 && xb+0 < WW) v.x = row[xb+0];
                if (xb+1 >= 0 && xb+1 < WW) v.y = row[xb+1];
                if (xb+2 >= 0 && xb+2 < WW) v.z = row[xb+2];
                if (xb+3 >= 0 && xb+3 < WW) v.w = row[xb+3];
            }
            if (!L1) {      // pad stays 0 (matches zero-padding semantics)
                v.x = fmaxf(fmaf(v.x, sc, sh), 0.f);
                v.y = fmaxf(fmaf(v.y, sc, sh), 0.f);
                v.z = fmaxf(fmaf(v.z, sc, sh), 0.f);
                v.w = fmaxf(fmaf(v.w, sc, sh), 0.f);
            }
        }
        float* plane = lds + (c >> 2)*PLANE;
        int cl = c & 3;
        int base = (rr*BCOL + 4*q)*4 + cl;
        plane[base + 0]  = v.x;
        plane[base + 4]  = v.y;
        plane[base + 8]  = v.z;
        plane[base + 12] = v.w;
    }
    __syncthreads();

    // ---- offset conv: om[27] ----
    float om[27];
    #pragma unroll
    for (int o = 0; o < 27; o++) om[o] = bo[o];

    #pragma unroll
    for (int t = 0; t < 9; t++) {
        const int rr = ly + 2 + (t/3) - 1, cc = lx + 2 + (t%3) - 1;
        const int pix = (rr*BCOL + cc)*4;
        const float* wt = wo + t*CIN2*27;
        float4 n = *reinterpret_cast<const float4*>(&lds[pix]);   // chunk 0
        #pragma unroll 1
        for (int c4 = 0; c4 < 5; c4++) {
            float4 nn = make_float4(0.f, 0.f, 0.f, 0.f);
            if (c4 < 4)
                nn = *reinterpret_cast<const float4*>(&lds[(c4+1)*PLANE + pix]);
            const float* wc = wt + c4*4*27;
            #pragma unroll
            for (int j = 0; j < 4; j++) {
                float nv = (&n.x)[j];
                #pragma unroll
                for (int o = 0; o < 27; o++) om[o] = fmaf(nv, wc[j*27 + o], om[o]);
            }
            n = nn;
        }
    }

    // ---- deformable sampling + tap matvec ----
    float acc[COUT];
    #pragma unroll
    for (int o = 0; o < COUT; o++) acc[o] = 0.f;

    #pragma unroll
    for (int k = 0; k < 9; k++) {
        float m  = sigf(om[18 + k]);
        float ys = (float)(h + k/3 - 1) + om[2*k];
        float xs = (float)(w + k%3 - 1) + om[2*k + 1];
        float y0f = floorf(ys), x0f = floorf(xs);
        int iy = (int)y0f, ix = (int)x0f;
        float fy = ys - y0f, fx = xs - x0f;
        bool vy0 = (iy >= 0) && (iy < HH);
        bool vy1 = (iy >= -1) && (iy < HH-1);
        bool vx0 = (ix >= 0) && (ix < WW);
        bool vx1 = (ix >= -1) && (ix < WW-1);
        float w00 = (vy0 && vx0) ? (1.f-fy)*(1.f-fx)*m : 0.f;
        float w01 = (vy0 && vx1) ? (1.f-fy)*fx*m       : 0.f;
        float w10 = (vy1 && vx0) ? fy*(1.f-fx)*m       : 0.f;
        float w11 = (vy1 && vx1) ? fy*fx*m             : 0.f;
        int cy0 = min(max(iy,   0), HH-1), cy1 = min(max(iy+1, 0), HH-1);
        int cx0 = min(max(ix,   0), WW-1), cx1 = min(max(ix+1, 0), WW-1);
        const float* wk = wd + k*CIN2*COUT;

        bool staged = (cy0 >= r0) && (cy1 <= r0 + BOX-1) &&
                      (cx0 >= c0) && (cx1 <= c0 + BOX-1);
        if (staged) {
            const int p00 = ((cy0-r0)*BCOL + (cx0-c0))*4;
            const int p01 = ((cy0-r0)*BCOL + (cx1-c0))*4;
            const int p10 = ((cy1-r0)*BCOL + (cx0-c0))*4;
            const int p11 = ((cy1-r0)*BCOL + (cx1-c0))*4;
            // rotation prefetch: load chunk c4+1 while FMA-ing chunk c4
            float4 a  = *reinterpret_cast<const float4*>(lds + p00);
            float4 bq = *reinterpret_cast<const float4*>(lds + p01);
            float4 cq = *reinterpret_cast<const float4*>(lds + p10);
            float4 dq = *reinterpret_cast<const float4*>(lds + p11);
            #pragma unroll 1
            for (int c4 = 0; c4 < 5; c4++) {
                float4 a2 = make_float4(0.f,0.f,0.f,0.f);
                float4 b2 = a2, c2 = a2, d2 = a2;
                if (c4 < 4) {
                    const float* pl = lds + (c4+1)*PLANE;
                    a2 = *reinterpret_cast<const float4*>(pl + p00);
                    b2 = *reinterpret_cast<const float4*>(pl + p01);
                    c2 = *reinterpret_cast<const float4*>(pl + p10);
                    d2 = *reinterpret_cast<const float4*>(pl + p11);
                }
                const float* wc = wk + c4*4*COUT;
                #pragma unroll
                for (int j = 0; j < 4; j++) {
                    float s = w00*(&a.x)[j] + w01*(&bq.x)[j]
                            + w10*(&cq.x)[j] + w11*(&dq.x)[j];
                    #pragma unroll
                    for (int o = 0; o < COUT; o++)
                        acc[o] = fmaf(s, wc[j*COUT + o], acc[o]);
                }
                a = a2; bq = b2; cq = c2; dq = d2;
            }
        } else {
            int o00 = cy0*WW + cx0, o01 = cy0*WW + cx1;
            int o10 = cy1*WW + cx0, o11 = cy1*WW + cx1;
            #pragma unroll 1
            for (int c = 0; c < CIN2; c++) {
                const float* src;
                float sc = 1.f, sh = 0.f;
                if (L1) {
                    int part = (c < NHID) ? esrc[e] : edst[e];
                    int ch   = (c < NHID) ? c : c - NHID;
                    src = xp + ((size_t)(part*BB + b)*NHID + ch)*HWD;
                } else {
                    src = xin + (size_t)c*HWD;
                    sc = bnS[e*CIN2 + c]; sh = bnT[e*CIN2 + c];
                }
                float av = src[o00], bv = src[o01], cv = src[o10], dv = src[o11];
                if (!L1) {
                    av = fmaxf(fmaf(av, sc, sh), 0.f); bv = fmaxf(fmaf(bv, sc, sh), 0.f);
                    cv = fmaxf(fmaf(cv, sc, sh), 0.f); dv = fmaxf(fmaf(dv, sc, sh), 0.f);
                }
                float s = w00*av + w01*bv + w10*cv + w11*dv;
                const float* wc = wk + c*COUT;
                #pragma unroll
                for (int o = 0; o < COUT; o++) acc[o] = fmaf(s, wc[o], acc[o]);
            }
        }
    }

    float* op = out + ((size_t)(e*BB + b)*COUT)*HWD + h*WW + w;
    #pragma unroll
    for (int o = 0; o < COUT; o++) op[(size_t)o*HWD] = acc[o];
}

// ---------------------------------------------------------------------------
// BN statistics (training mode, biased var, eps=1e-5), folding gamma/beta:
//   scale = g*rstd, shift = beta - mean*scale
// ---------------------------------------------------------------------------
__device__ __forceinline__ void bn_finish(float s1, float s2, int n, float g, float bt,
                                          float* scale, float* shift, int idx)
{
    float mean = s1 / (float)n;
    float var  = fmaxf(s2 / (float)n - mean*mean, 0.f);
    float rs   = rsqrtf(var + 1e-5f);
    scale[idx] = g * rs;
    shift[idx] = bt - mean * g * rs;
}

// stats over flat layout [G][B][C][HWD]; one block per (g,c); grid = G*C
template<int C>
__global__ __launch_bounds__(256)
void bn_stats_flat(const float* __restrict__ x, const float* __restrict__ gamma,
                   const float* __restrict__ beta, float* __restrict__ scale,
                   float* __restrict__ shift)
{
    const int gc = blockIdx.x;
    const int g = gc / C, c = gc % C;
    const int N = BB * HWD;
    float s1 = 0.f, s2 = 0.f;
    for (int idx = threadIdx.x; idx < N; idx += 256) {
        int b = idx / HWD, p = idx % HWD;
        float v = x[((size_t)(g*BB + b)*C + c)*HWD + p];
        s1 += v; s2 += v*v;
    }
    __shared__ float r1[256], r2[256];
    r1[threadIdx.x] = s1; r2[threadIdx.x] = s2;
    __syncthreads();
    for (int s = 128; s > 0; s >>= 1) {
        if (threadIdx.x < s) { r1[threadIdx.x] += r1[threadIdx.x+s]; r2[threadIdx.x] += r2[threadIdx.x+s]; }
        __syncthreads();
    }
    if (threadIdx.x == 0)
        bn_finish(r1[0], r2[0], N, gamma[gc], beta[gc], scale, shift, gc);
}

// ---------------------------------------------------------------------------
// Edge message: msg = sigmoid(out_w . relu(bn2(t2)) + out_b) *
//                     (1 - sigmoid(a_w . xp[src] + a_b))
// grid: (36, B, E)
// ---------------------------------------------------------------------------
__global__ __launch_bounds__(256)
void msg_kernel(const float* __restrict__ t2, const float* __restrict__ s2,
                const float* __restrict__ sh2, const float* __restrict__ o_w,
                const float* __restrict__ o_b, const float* __restrict__ a_w,
                const float* __restrict__ a_b, const float* __restrict__ xp,
                const int* __restrict__ esrc, float* __restrict__ msg)
{
    int px = blockIdx.x * 256 + threadIdx.x;
    int b = blockIdx.y, e = blockIdx.z;
    float sab = o_b[e];
    #pragma unroll
    for (int c = 0; c < NHID; c++) {
        float v = t2[((size_t)(e*BB + b)*NHID + c)*HWD + px];
        v = fmaxf(fmaf(v, s2[e*NHID+c], sh2[e*NHID+c]), 0.f);
        sab += v * o_w[e*NHID + c];
    }
    int sp = esrc[e];
    float sa = a_b[e];
    #pragma unroll
    for (int c = 0; c < NHID; c++)
        sa += xp[((size_t)(sp*BB + b)*NHID + c)*HWD + px] * a_w[e*NHID + c];
    msg[((size_t)e*BB + b)*HWD + px] = sigf(sab) * (1.f - sigf(sa));
}

// ---------------------------------------------------------------------------
// gate[p,b,hw] = 1 + decomp + self_att + sum_{e: dst==p} msg[e]
// grid: (36, B, P)
// ---------------------------------------------------------------------------
__global__ __launch_bounds__(256)
void gate_kernel(const float* __restrict__ xp, const float* __restrict__ xh,
                 const float* __restrict__ att_w, const float* __restrict__ att_b,
                 const float* __restrict__ du_w, const float* __restrict__ du_b,
                 const float* __restrict__ dl_w, const float* __restrict__ dl_b,
                 const int* __restrict__ edst, const float* __restrict__ msg,
                 float* __restrict__ gate)
{
    int px = blockIdx.x * 256 + threadIdx.x;
    int b = blockIdx.y, p = blockIdx.z;
    float s = att_b[p];
    #pragma unroll
    for (int c = 0; c < NHID; c++)
        s += xp[((size_t)(p*BB + b)*NHID + c)*HWD + px] * att_w[p*NHID + c];
    float satt = sigf(s);
    int hs = (p < 4) ? 0 : 1;
    const float* dw = (p < 4) ? du_w : dl_w;
    float d = (p < 4) ? du_b[0] : dl_b[0];
    #pragma unroll
    for (int c = 0; c < NHID; c++)
        d += xh[((size_t)(hs*BB + b)*NHID + c)*HWD + px] * dw[c];
    float dec = sigf(d);
    float xpp = 0.f;
    for (int e = 0; e < NE; e++)
        if (edst[e] == p) xpp += msg[((size_t)e*BB + b)*HWD + px];
    gate[((size_t)p*BB + b)*HWD + px] = 1.f + dec + satt + xpp;
}

// ---------------------------------------------------------------------------
// y[p,b,o,hw] = gate[p,b,hw] * sum_c p_fea[b,c,hw] * upd_w[p,o,c]
// grid: (36, B, P)
// ---------------------------------------------------------------------------
__global__ __launch_bounds__(256)
void q_kernel(const float* __restrict__ p_fea, const float* __restrict__ wq_all,
              const float* __restrict__ gate, float* __restrict__ y)
{
    int px = blockIdx.x * 256 + threadIdx.x;
    int b = blockIdx.y, p = blockIdx.z;
    const float* wq = wq_all + (size_t)p*NIN*NHID;     // [c][o]
    const float* pf = p_fea + (size_t)b*NIN*HWD + px;
    float acc[NHID];
    #pragma unroll
    for (int o = 0; o < NHID; o++) acc[o] = 0.f;
    for (int c = 0; c < NIN; c++) {
        float v = pf[(size_t)c*HWD];
        const float* wc = wq + c*NHID;
        #pragma unroll
        for (int o = 0; o < NHID; o++) acc[o] = fmaf(v, wc[o], acc[o]);
    }
    float g = gate[((size_t)p*BB + b)*HWD + px];
    float* yp = y + ((size_t)(p*BB + b)*NHID)*HWD + px;
    #pragma unroll
    for (int o = 0; o < NHID; o++) yp[(size_t)o*HWD] = acc[o] * g;
}

// ---------------------------------------------------------------------------
// out = relu(bn5(y));   grid: (36, B*HID, P)
// ---------------------------------------------------------------------------
__global__ __launch_bounds__(256)
void out_kernel(const float* __restrict__ y, const float* __restrict__ s5,
                const float* __restrict__ t5, float* __restrict__ out)
{
    int px = blockIdx.x * 256 + threadIdx.x;
    int bo = blockIdx.y, p = blockIdx.z;
    int b = bo / NHID, o = bo % NHID;
    size_t idx = ((size_t)(p*BB + b)*NHID + o)*HWD + px;
    out[idx] = fmaxf(fmaf(y[idx], s5[p*NHID+o], t5[p*NHID+o]), 0.f);
}

// ---------------------------------------------------------------------------
// launcher
// ---------------------------------------------------------------------------
extern "C" void kernel_launch(void* const* d_in, const int* in_sizes, int n_in,
                              void* d_out, int out_size, void* d_ws, size_t ws_size,
                              hipStream_t stream)
{
    (void)in_sizes; (void)n_in; (void)out_size; (void)ws_size;

    const float* p_fea  = (const float*)d_in[0];
    const float* xp     = (const float*)d_in[1];
    const float* xh     = (const float*)d_in[2];
    const float* att_w  = (const float*)d_in[3];
    const float* att_b  = (const float*)d_in[4];
    const float* du_w   = (const float*)d_in[5];
    const float* du_b   = (const float*)d_in[6];
    const float* dl_w   = (const float*)d_in[7];
    const float* dl_b   = (const float*)d_in[8];
    const float* upd_w  = (const float*)d_in[9];
    const float* upd_g  = (const float*)d_in[10];
    const float* upd_b  = (const float*)d_in[11];
    const float* off1_w = (const float*)d_in[12];
    const float* off1_b = (const float*)d_in[13];
    const float* dcn1_w = (const float*)d_in[14];
    const float* bn1_g  = (const float*)d_in[15];
    const float* bn1_b  = (const float*)d_in[16];
    const float* off2_w = (const float*)d_in[17];
    const float* off2_b = (const float*)d_in[18];
    const float* dcn2_w = (const float*)d_in[19];
    const float* bn2_g  = (const float*)d_in[20];
    const float* bn2_b  = (const float*)d_in[21];
    const float* out_w  = (const float*)d_in[22];
    const float* out_b  = (const float*)d_in[23];
    const float* aatt_w = (const float*)d_in[24];
    const float* aatt_b = (const float*)d_in[25];
    const int* esrc     = (const int*)d_in[26];
    const int* edst     = (const int*)d_in[27];
    float* outp = (float*)d_out;
    float* ws = (float*)d_ws;

    // workspace layout (float offsets)
    constexpr size_t o_x1   = 0;                                    // [E][B][20][HWD]
    constexpr size_t o_t2   = o_x1  + (size_t)NE*BB*CIN2*HWD;       // [E][B][10][HWD]
    constexpr size_t o_msg  = o_t2  + (size_t)NE*BB*NHID*HWD;
    constexpr size_t o_gate = o_msg  + (size_t)NE*BB*HWD;
    constexpr size_t o_w1   = o_gate + (size_t)NPART*BB*HWD;
    constexpr size_t o_b1   = o_w1   + 58320;
    constexpr size_t o_d1   = o_b1   + 324;
    constexpr size_t o_w2   = o_d1   + 43200;
    constexpr size_t o_b2   = o_w2   + 58320;
    constexpr size_t o_d2   = o_b2   + 324;
    constexpr size_t o_uw   = o_d2   + 21600;
    constexpr size_t o_bn1s = o_uw   + 15360;
    constexpr size_t o_bn1t = o_bn1s + NE*CIN2;
    constexpr size_t o_bn2s = o_bn1t + NE*CIN2;
    constexpr size_t o_bn2t = o_bn2s + NE*NHID;
    constexpr size_t o_bn5s = o_bn2t + NE*NHID;
    constexpr size_t o_bn5t = o_bn5s + NPART*NHID;
    constexpr size_t o_y    = o_bn5t + NPART*NHID;                  // [P][B][10][HWD]
    float* x1 = ws + o_x1;
    float* t2 = ws + o_t2;
    float* y  = ws + o_y;

    xpose_weights<<<dim3(772), 256, 0, stream>>>(
        off1_w, off1_b, dcn1_w, off2_w, off2_b, dcn2_w, upd_w,
        ws+o_w1, ws+o_b1, ws+o_d1, ws+o_w2, ws+o_b2, ws+o_d2, ws+o_uw);

    dcn_tiled<CIN2, true><<<dim3(36, BB, NE), 256, 0, stream>>>(
        nullptr, xp, esrc, edst, ws+o_w1, ws+o_b1, ws+o_d1,
        nullptr, nullptr, x1);

    bn_stats_flat<CIN2><<<dim3(NE*CIN2), 256, 0, stream>>>(
        x1, bn1_g, bn1_b, ws+o_bn1s, ws+o_bn1t);

    dcn_tiled<NHID, false><<<dim3(36, BB, NE), 256, 0, stream>>>(
        x1, nullptr, esrc, edst, ws+o_w2, ws+o_b2, ws+o_d2,
        ws+o_bn1s, ws+o_bn1t, t2);

    bn_stats_flat<NHID><<<dim3(NE*NHID), 256, 0, stream>>>(
        t2, bn2_g, bn2_b, ws+o_bn2s, ws+o_bn2t);

    msg_kernel<<<dim3(36, BB, NE), 256, 0, stream>>>(
        t2, ws+o_bn2s, ws+o_bn2t, out_w, out_b, aatt_w, aatt_b, xp, esrc, ws+o_msg);

    gate_kernel<<<dim3(36, BB, NPART), 256, 0, stream>>>(
        xp, xh, att_w, att_b, du_w, du_b, dl_w, dl_b, edst, ws+o_msg, ws+o_gate);

    q_kernel<<<dim3(36, BB, NPART), 256, 0, stream>>>(
        p_fea, ws+o_uw, ws+o_gate, y);

    bn_stats_flat<NHID><<<dim3(NPART*NHID), 256, 0, stream>>>(
        y, upd_g, upd_b, ws+o_bn5s, ws+o_bn5t);

    out_kernel<<<dim3(36, BB*NHID, NPART), 256, 0, stream>>>(
        y, ws+o_bn5s, ws+o_bn5t, outp);
}